// Round 5
// baseline (543.821 us; speedup 1.0000x reference)
//
#include <hip/hip_runtime.h>

#define K_DIM 7168
#define N_DIM 4096
#define KBLKS 56   // K/128
#define FP8MAX 448.0f
#define BM 256
#define BN 256

typedef float f32x4 __attribute__((ext_vector_type(4)));

#define GLOBAL_AS __attribute__((address_space(1)))
#define LDS_AS __attribute__((address_space(3)))

__device__ __forceinline__ void gload_lds16(const void* g, void* l) {
  __builtin_amdgcn_global_load_lds((GLOBAL_AS void*)g, (LDS_AS void*)l, 16, 0, 0);
}

__device__ __forceinline__ int pack_fp8x4(float a, float b, float c, float d) {
  int v = __builtin_amdgcn_cvt_pk_fp8_f32(a, b, 0, false);
  v = __builtin_amdgcn_cvt_pk_fp8_f32(c, d, v, true);
  return v;
}

// ---- fused quant: region 0 = weight f32->fp8 cast, region 1 = activation blockwise quant ----
__global__ void quant_fused(const float* __restrict__ x, const float* __restrict__ w,
                            unsigned char* __restrict__ xq, unsigned char* __restrict__ wq,
                            float* __restrict__ asT, int M, long nw4) {
  long gidx = (long)blockIdx.x * blockDim.x + threadIdx.x;
  if (gidx < nw4) {   // weight cast: values already exactly fp8-representable
    float4 v = *(const float4*)(w + gidx * 4);
    ((int*)wq)[gidx] = pack_fp8x4(v.x, v.y, v.z, v.w);
    return;
  }
  long t = gidx - nw4;
  int gid = (int)(t >> 5);          // one 32-lane group per 128-block
  int lane = (int)t & 31;
  if (gid >= M * KBLKS) return;
  int m = gid / KBLKS;
  int kb = gid - m * KBLKS;
  size_t off = (size_t)m * K_DIM + kb * 128 + lane * 4;
  float4 v = *(const float4*)(x + off);
  float amax = fmaxf(fmaxf(fabsf(v.x), fabsf(v.y)), fmaxf(fabsf(v.z), fabsf(v.w)));
#pragma unroll
  for (int d = 16; d; d >>= 1) amax = fmaxf(amax, __shfl_xor(amax, d));
  float scale = fmaxf(amax, 1e-12f) / FP8MAX;   // exact reference semantics
  *(int*)(xq + off) = pack_fp8x4(v.x / scale, v.y / scale, v.z / scale, v.w / scale);
  if (lane == 0) asT[(size_t)kb * M + m] = scale;
}

// ---- 256x256 8-phase fp8 blockwise-scaled GEMM (m201 template port) ----
// 8 waves (2M x 4N), per-wave 128x64. BK=128 == scale block. LDS 2x(32K A + 32K B) dbuf.
// Fragment-major LDS layout, slot^=(row&7) swizzle on BOTH stage-source and ds_read.
__global__ __launch_bounds__(512, 2)
void gemm_fp8_blk(const unsigned char* __restrict__ xq,
                  const unsigned char* __restrict__ wq,
                  const float* __restrict__ asT,
                  const float* __restrict__ wscale,
                  float* __restrict__ out, int M) {
  __shared__ unsigned char ldsA[2][32768];
  __shared__ unsigned char ldsB[2][32768];
  __shared__ float ldsAS[2][256];

  const int bid = blockIdx.x;
  const int nbn = N_DIM / BN;                    // 16
  const int per = (M / BM) * nbn >> 3;           // grid/8
  const int swz = (bid & 7) * per + (bid >> 3);  // XCD-aware (grid%8==0)
  const int m0 = (swz / nbn) * BM, n0 = (swz % nbn) * BN;

  const int tid = threadIdx.x;
  const int wv = tid >> 6, lane = tid & 63;
  const int wm = (wv >> 2) * 128;
  const int wn = (wv & 3) * 64;
  const int rsel = lane & 15;
  const int ks = lane >> 4;
  const int j0 = ks >> 1, h8 = (ks & 1) * 8;
  const int jrow = ks * 4;

  // swizzled per-lane k-slot byte offsets within a 128B LDS row, kk=0..3
  int swk[4];
#pragma unroll
  for (int kk = 0; kk < 4; ++kk)
    swk[kk] = (((kk * 2 + j0) ^ (rsel & 7)) * 16) + h8;

  // staging chunk map: LDS o = it*8192 + wv*1024 + lane*16 (linear dest);
  // global col pre-inverse-swizzled so read-side swizzle sees linear data
  int srow[4], scol[4];
#pragma unroll
  for (int it = 0; it < 4; ++it) {
    int o = it * 8192 + wv * 1024 + lane * 16;
    int r = o >> 7, sl = (o >> 4) & 7;
    srow[it] = r;
    scol[it] = (sl ^ (r & 7)) * 16;
  }

  f32x4 acc[8][4] = {};

  auto stageA = [&](int t1, int b, int it) {
    gload_lds16(xq + (size_t)(m0 + srow[it]) * K_DIM + (size_t)t1 * 128 + scol[it],
                &ldsA[b][it * 8192 + wv * 1024]);
  };
  auto stageB = [&](int t1, int b, int it) {
    gload_lds16(wq + (size_t)(n0 + srow[it]) * K_DIM + (size_t)t1 * 128 + scol[it],
                &ldsB[b][it * 8192 + wv * 1024]);
  };
  auto stageS = [&](int t1, int b) {
    if (wv == 0) gload_lds16(asT + (size_t)t1 * M + m0 + lane * 4, &ldsAS[b][0]);
  };

#pragma unroll
  for (int it = 0; it < 4; ++it) { stageA(0, 0, it); stageB(0, 0, it); }
  stageS(0, 0);
  asm volatile("s_waitcnt vmcnt(0)" ::: "memory");
  __builtin_amdgcn_s_barrier();

  for (int t = 0; t < KBLKS; ++t) {
    const int cur = t & 1;
    const unsigned char* pA0 = &ldsA[cur][(wm + rsel) * 128];
    const unsigned char* pB0 = &ldsB[cur][(wn + rsel) * 128];
    const float wsv = wscale[(size_t)((n0 + wn) >> 7) * KBLKS + t];  // wave-uniform
    const bool pf = (t + 1 < KBLKS);

#pragma unroll
    for (int mh = 0; mh < 2; ++mh) {
#pragma unroll
      for (int nh = 0; nh < 2; ++nh) {
        f32x4 tmp[4][2];
#pragma unroll
        for (int kh = 0; kh < 2; ++kh) {
          const int p = mh * 4 + nh * 2 + kh;
          // 12 x ds_read_b64 (8 A + 4 B), swizzled
          long a[4][2], b[2][2];
#pragma unroll
          for (int mi = 0; mi < 4; ++mi)
#pragma unroll
            for (int q = 0; q < 2; ++q)
              a[mi][q] = *(const long*)(pA0 + mh * 8192 + mi * 2048 + swk[kh * 2 + q]);
#pragma unroll
          for (int ni = 0; ni < 2; ++ni)
#pragma unroll
            for (int q = 0; q < 2; ++q)
              b[ni][q] = *(const long*)(pB0 + nh * 4096 + ni * 2048 + swk[kh * 2 + q]);

          // prefetch next K-tile, 2 gloads/phase in phases 0-3 (in flight across barriers)
          if (pf) {
            if (p == 0) { stageA(t + 1, cur ^ 1, 0); stageA(t + 1, cur ^ 1, 1); stageS(t + 1, cur ^ 1); }
            if (p == 1) { stageA(t + 1, cur ^ 1, 2); stageA(t + 1, cur ^ 1, 3); }
            if (p == 2) { stageB(t + 1, cur ^ 1, 0); stageB(t + 1, cur ^ 1, 1); }
            if (p == 3) { stageB(t + 1, cur ^ 1, 2); stageB(t + 1, cur ^ 1, 3); }
          }
          __builtin_amdgcn_s_barrier();
          __builtin_amdgcn_s_setprio(1);
#pragma unroll
          for (int mi = 0; mi < 4; ++mi)
#pragma unroll
            for (int ni = 0; ni < 2; ++ni) {
              f32x4 t4 = (kh == 0) ? (f32x4){0.f, 0.f, 0.f, 0.f} : tmp[mi][ni];
              t4 = __builtin_amdgcn_mfma_f32_16x16x32_fp8_fp8(a[mi][0], b[ni][0], t4, 0, 0, 0);
              t4 = __builtin_amdgcn_mfma_f32_16x16x32_fp8_fp8(a[mi][1], b[ni][1], t4, 0, 0, 0);
              tmp[mi][ni] = t4;
            }
          __builtin_amdgcn_s_setprio(0);
          __builtin_amdgcn_s_barrier();
        }
        // apply per-128-block scales to this quadrant: acc += tmp * (a_scale * w_scale)
        const float* pAS = &ldsAS[cur][wm + mh * 64 + jrow];
#pragma unroll
        for (int mi = 0; mi < 4; ++mi) {
          f32x4 as4 = *(const f32x4*)(pAS + mi * 16);
          f32x4 comb = as4 * wsv;
#pragma unroll
          for (int ni = 0; ni < 2; ++ni)
            acc[mh * 4 + mi][nh * 2 + ni] += tmp[mi][ni] * comb;
        }
      }
    }
    // K-tile boundary: next tile's 8 loads (issued >=4 phases ago) must be resident
    asm volatile("s_waitcnt vmcnt(0)" ::: "memory");
    __builtin_amdgcn_s_barrier();
  }

  // epilogue: C/D layout col=lane&15, row=(lane>>4)*4+reg
#pragma unroll
  for (int mi = 0; mi < 8; ++mi) {
#pragma unroll
    for (int j = 0; j < 4; ++j) {
      float* op = out + (size_t)(m0 + wm + mi * 16 + jrow + j) * N_DIM + n0 + wn + rsel;
#pragma unroll
      for (int ni = 0; ni < 4; ++ni) op[ni * 16] = acc[mi][ni][j];
    }
  }
}

extern "C" void kernel_launch(void* const* d_in, const int* in_sizes, int n_in,
                              void* d_out, int out_size, void* d_ws, size_t ws_size,
                              hipStream_t stream) {
  const float* x   = (const float*)d_in[0];
  const float* wgt = (const float*)d_in[1];
  const float* wsc = (const float*)d_in[2];
  float* out = (float*)d_out;

  const int K = K_DIM, N = N_DIM;
  const int M = in_sizes[0] / K;                 // 4096

  unsigned char* xq = (unsigned char*)d_ws;      // M*K fp8
  unsigned char* wq = xq + (size_t)M * K;        // N*K fp8
  float* asT = (float*)(wq + (size_t)N * K);     // [KBLKS][M] f32

  long nw4 = (long)N * K / 4;
  long nx  = (long)M * KBLKS * 32;
  long tot = nw4 + nx;
  quant_fused<<<(int)((tot + 255) / 256), 256, 0, stream>>>(x, wgt, xq, wq, asT, M, nw4);

  dim3 grid((M / BM) * (N / BN));                // 256
  gemm_fp8_blk<<<grid, 512, 0, stream>>>(xq, wq, asT, wsc, out, M);
}

// Round 6
// 487.257 us; speedup vs baseline: 1.1161x; 1.1161x over previous
//
#include <hip/hip_runtime.h>

#define K_DIM 7168
#define N_DIM 4096
#define KBLKS 56   // K/128
#define FP8MAX 448.0f
#define BM 256
#define BN 256

typedef float f32x4 __attribute__((ext_vector_type(4)));

#define GLOBAL_AS __attribute__((address_space(1)))
#define LDS_AS __attribute__((address_space(3)))

__device__ __forceinline__ void gload_lds16(const void* g, void* l) {
  __builtin_amdgcn_global_load_lds((GLOBAL_AS void*)g, (LDS_AS void*)l, 16, 0, 0);
}

__device__ __forceinline__ int pack_fp8x4(float a, float b, float c, float d) {
  int v = __builtin_amdgcn_cvt_pk_fp8_f32(a, b, 0, false);
  v = __builtin_amdgcn_cvt_pk_fp8_f32(c, d, v, true);
  return v;
}

// ---- fused quant: region 0 = weight f32->fp8 cast, region 1 = activation blockwise quant ----
__global__ void quant_fused(const float* __restrict__ x, const float* __restrict__ w,
                            unsigned char* __restrict__ xq, unsigned char* __restrict__ wq,
                            float* __restrict__ asT, int M, long nw4) {
  long gidx = (long)blockIdx.x * blockDim.x + threadIdx.x;
  if (gidx < nw4) {   // weight cast: values already exactly fp8-representable
    float4 v = *(const float4*)(w + gidx * 4);
    ((int*)wq)[gidx] = pack_fp8x4(v.x, v.y, v.z, v.w);
    return;
  }
  long t = gidx - nw4;
  int gid = (int)(t >> 5);          // one 32-lane group per 128-block
  int lane = (int)t & 31;
  if (gid >= M * KBLKS) return;
  int m = gid / KBLKS;
  int kb = gid - m * KBLKS;
  size_t off = (size_t)m * K_DIM + kb * 128 + lane * 4;
  float4 v = *(const float4*)(x + off);
  float amax = fmaxf(fmaxf(fabsf(v.x), fabsf(v.y)), fmaxf(fabsf(v.z), fabsf(v.w)));
#pragma unroll
  for (int d = 16; d; d >>= 1) amax = fmaxf(amax, __shfl_xor(amax, d));
  float am = fmaxf(amax, 1e-12f);
  float scale = am / FP8MAX;        // exact reference scale (RNE divide)
  float inv = FP8MAX / am;          // correctly-rounded reciprocal-scale (saves 3 divides)
  *(int*)(xq + off) = pack_fp8x4(v.x * inv, v.y * inv, v.z * inv, v.w * inv);
  if (lane == 0) asT[(size_t)kb * M + m] = scale;
}

// ---- 256x256 fp8 blockwise-scaled GEMM, register-resident fragments ----
// 8 waves (2M x 4N), wave tile 128x64, BK=128 == scale block.
// LDS fragment-major layout [tile16][kk][r*32 + s*8], s = g ^ 2*((r>>2)&1):
//   - gload_lds chunks (16B) map to contiguous global 16B (verified both orders)
//   - ds_read_b64 banking: <=2-way per quarter-wave (free tier)
// Each fragment read from LDS exactly ONCE per kstep (no nh/mh redundancy).
// ONE barrier + one vmcnt(0) per kstep; prefetch issued at kstep start has
// ~5k cycles of MFMA cover -> drain is free.
__global__ __launch_bounds__(512, 2)
void gemm_fp8_blk(const unsigned char* __restrict__ xq,
                  const unsigned char* __restrict__ wq,
                  const float* __restrict__ asT,
                  const float* __restrict__ wscale,
                  float* __restrict__ out, int M) {
  __shared__ unsigned char ldsA[2][32768];
  __shared__ unsigned char ldsB[2][32768];
  __shared__ float ldsAS[2][256];

  const int bid = blockIdx.x;
  const int nbn = N_DIM / BN;                    // 16
  const int per = (M / BM) * nbn >> 3;           // grid/8
  const int swz = (bid & 7) * per + (bid >> 3);  // XCD-aware (grid%8==0)
  const int m0 = (swz / nbn) * BM, n0 = (swz % nbn) * BN;

  const int tid = threadIdx.x;
  const int wv = tid >> 6, lane = tid & 63;
  const int wm = (wv >> 2) * 128;                // A half owned by this wave
  const int wn = (wv & 3) * 64;                  // B quarter owned by this wave
  const int rf = lane & 15, gf = lane >> 4;      // MFMA frag: row, k-slice
  const int jrow = gf * 4;                       // C/D row group
  // fragment byte offset within a [kk] 512B group; even-XOR bank swizzle
  const int fragoff = rf * 32 + ((gf ^ ((((rf >> 2) & 1)) << 1))) * 8;

  // staging chunk map: chunk c -> (tile mi, kk, row r, half h);
  // global col = kk*32 + (h ^ ((r>>2)&1))*16  (inverse of read-side swizzle)
  int srow[4], scol[4];
#pragma unroll
  for (int j = 0; j < 4; ++j) {
    int c = wv * 256 + j * 64 + lane;
    int mi = c >> 7, kk = (c >> 5) & 3, r = (c >> 1) & 15, h = c & 1;
    srow[j] = mi * 16 + r;
    scol[j] = kk * 32 + ((h ^ ((r >> 2) & 1)) << 4);
  }

  f32x4 acc[8][4] = {};
  const f32x4 z4 = {0.f, 0.f, 0.f, 0.f};

  auto stage = [&](int t1, int b) {
#pragma unroll
    for (int j = 0; j < 4; ++j)
      gload_lds16(xq + (size_t)(m0 + srow[j]) * K_DIM + t1 * 128 + scol[j],
                  &ldsA[b][wv * 4096 + j * 1024]);
#pragma unroll
    for (int j = 0; j < 4; ++j)
      gload_lds16(wq + (size_t)(n0 + srow[j]) * K_DIM + t1 * 128 + scol[j],
                  &ldsB[b][wv * 4096 + j * 1024]);
    if (wv == 0) gload_lds16(asT + (size_t)t1 * M + m0 + lane * 4, &ldsAS[b][0]);
  };

  stage(0, 0);
  asm volatile("s_waitcnt vmcnt(0)" ::: "memory");
  __builtin_amdgcn_s_barrier();

  const int wsbase = ((n0 + wn) >> 7) * KBLKS;

  for (int t = 0; t < KBLKS; ++t) {
    const int cur = t & 1;
    if (t + 1 < KBLKS) stage(t + 1, cur ^ 1);   // prefetch early: max in-flight cover

    const unsigned char* pA = &ldsA[cur][(wm >> 4) * 2048 + fragoff];
    const unsigned char* pB = &ldsB[cur][(wv & 3) * 8192 + fragoff];
    const float wsv = wscale[wsbase + t];        // wave-uniform scalar
    const float* pAS = &ldsAS[cur][wm + jrow];

    // B fragments: 16 x ds_read_b64, each read exactly once per kstep
    long bfr[4][4];
#pragma unroll
    for (int ni = 0; ni < 4; ++ni)
#pragma unroll
      for (int kk = 0; kk < 4; ++kk)
        bfr[ni][kk] = *(const long*)(pB + ni * 2048 + kk * 512);

#pragma unroll
    for (int mi = 0; mi < 8; ++mi) {
      long af[4];
#pragma unroll
      for (int kk = 0; kk < 4; ++kk)
        af[kk] = *(const long*)(pA + mi * 2048 + kk * 512);
      f32x4 as4 = *(const f32x4*)(pAS + mi * 16);
      f32x4 comb = as4 * wsv;
#pragma unroll
      for (int ni = 0; ni < 4; ++ni) {
        f32x4 tp = __builtin_amdgcn_mfma_f32_16x16x32_fp8_fp8(af[0], bfr[ni][0], z4, 0, 0, 0);
        tp = __builtin_amdgcn_mfma_f32_16x16x32_fp8_fp8(af[1], bfr[ni][1], tp, 0, 0, 0);
        tp = __builtin_amdgcn_mfma_f32_16x16x32_fp8_fp8(af[2], bfr[ni][2], tp, 0, 0, 0);
        tp = __builtin_amdgcn_mfma_f32_16x16x32_fp8_fp8(af[3], bfr[ni][3], tp, 0, 0, 0);
        acc[mi][ni] += tp * comb;                // per-128-block scale apply
      }
    }

    // own prefetch (issued ~5k cycles ago) long since landed -> cheap drain
    asm volatile("s_waitcnt vmcnt(0)" ::: "memory");
    __builtin_amdgcn_s_barrier();
  }

  // epilogue: C/D layout col=lane&15, row=(lane>>4)*4+reg
#pragma unroll
  for (int mi = 0; mi < 8; ++mi) {
#pragma unroll
    for (int j = 0; j < 4; ++j) {
      float* op = out + (size_t)(m0 + wm + mi * 16 + jrow + j) * N_DIM + n0 + wn + rf;
#pragma unroll
      for (int ni = 0; ni < 4; ++ni) op[ni * 16] = acc[mi][ni][j];
    }
  }
}

extern "C" void kernel_launch(void* const* d_in, const int* in_sizes, int n_in,
                              void* d_out, int out_size, void* d_ws, size_t ws_size,
                              hipStream_t stream) {
  const float* x   = (const float*)d_in[0];
  const float* wgt = (const float*)d_in[1];
  const float* wsc = (const float*)d_in[2];
  float* out = (float*)d_out;

  const int K = K_DIM, N = N_DIM;
  const int M = in_sizes[0] / K;                 // 4096

  unsigned char* xq = (unsigned char*)d_ws;      // M*K fp8
  unsigned char* wq = xq + (size_t)M * K;        // N*K fp8
  float* asT = (float*)(wq + (size_t)N * K);     // [KBLKS][M] f32

  long nw4 = (long)N * K / 4;
  long nx  = (long)M * KBLKS * 32;
  long tot = nw4 + nx;
  quant_fused<<<(int)((tot + 255) / 256), 256, 0, stream>>>(x, wgt, xq, wq, asT, M, nw4);

  dim3 grid((M / BM) * (N / BN));                // 256
  gemm_fp8_blk<<<grid, 512, 0, stream>>>(xq, wq, asT, wsc, out, M);
}